// Round 1
// baseline (202.851 us; speedup 1.0000x reference)
//
#include <hip/hip_runtime.h>
#include <hip/hip_bf16.h>

// Problem constants (fixed by the reference)
#define B_  16
#define LQ_ 1024
#define LK_ 1024
#define C_  512

typedef __attribute__((ext_vector_type(4))) float f32x4;
typedef __attribute__((ext_vector_type(8))) short bf16x8;

__device__ __forceinline__ float bf2f(ushort u) {
  union { unsigned int i; float f; } v; v.i = ((unsigned int)u) << 16; return v.f;
}
__device__ __forceinline__ ushort f2bf(float f) {
  union { float f; unsigned int i; } v; v.f = f;
  unsigned int r = v.i + 0x7fffu + ((v.i >> 16) & 1u);
  return (ushort)(r >> 16);
}
__device__ __forceinline__ float gelu_exact(float x) {
  return 0.5f * x * (1.0f + erff(x * 0.70710678118654752f));
}

// ---------------------------------------------------------------------------
// prep: fp32 row (len 512) -> bf16 row + fp32 L2 norm (of ORIGINAL values)
// one wave per row, 4 waves/block
__global__ __launch_bounds__(256) void prep_qk(const float* __restrict__ x,
                                               ushort* __restrict__ xb,
                                               float* __restrict__ norms) {
  int wid = blockIdx.x * 4 + (threadIdx.x >> 6);
  int lane = threadIdx.x & 63;
  const float* xr = x + (long)wid * C_;
  ushort* xo = xb + (long)wid * C_;
  float ss = 0.f;
#pragma unroll
  for (int i0 = 0; i0 < 2; ++i0) {
    int i = lane * 4 + i0 * 256;
    float4 v = *(const float4*)(xr + i);
    ss += v.x * v.x + v.y * v.y + v.z * v.z + v.w * v.w;
    ushort4 o;
    o.x = f2bf(v.x); o.y = f2bf(v.y); o.z = f2bf(v.z); o.w = f2bf(v.w);
    *(ushort4*)(xo + i) = o;
  }
#pragma unroll
  for (int off = 32; off > 0; off >>= 1) ss += __shfl_xor(ss, off);
  if (lane == 0) norms[wid] = sqrtf(ss);
}

// fp32 -> bf16 elementwise (n4 float4 chunks)
__global__ __launch_bounds__(256) void conv_bf16(const float* __restrict__ x,
                                                 ushort* __restrict__ o, int n4) {
  int i = blockIdx.x * 256 + threadIdx.x;
  if (i < n4) {
    float4 v = *(const float4*)(x + (long)i * 4);
    ushort4 u;
    u.x = f2bf(v.x); u.y = f2bf(v.y); u.z = f2bf(v.z); u.w = f2bf(v.w);
    *(ushort4*)(o + (long)i * 4) = u;
  }
}

// ---------------------------------------------------------------------------
// Batched NT GEMM: C[m,n] = epilogue( sum_k A[m,k]*B[n,k] )
// A: [M=1024 x K] bf16 rm, B: [N=1024 x K] bf16 rm, C: [1024 x 1024] bf16 rm.
// Tile 128x128, BK=32, 4 waves (2x2 of 64x64), 16x16x32 MFMA.
// EPI 0: v / (qn[row]*kn[col] + 1e-2)    EPI 1: exact gelu
#define BK 32
#define LDT 40  // 32 + 8 pad (keeps 16B alignment, bank-balanced)

template <int EPI>
__global__ __launch_bounds__(256, 2) void gemm_nt(
    const ushort* __restrict__ A, const ushort* __restrict__ Bm,
    ushort* __restrict__ Cc, int K, long sA, long sB, long sC,
    const float* __restrict__ qn, const float* __restrict__ kn) {
  int b = blockIdx.z;
  A += (long)b * sA;
  Bm += (long)b * sB;
  Cc += (long)b * sC;
  const int bm = blockIdx.y * 128, bn = blockIdx.x * 128;

  __shared__ ushort At[128][LDT];
  __shared__ ushort Bt[128][LDT];

  int tid = threadIdx.x;
  int lane = tid & 63, w = tid >> 6;
  int wr = w >> 1, wc = w & 1;
  int l16 = lane & 15, lhi = lane >> 4;

  f32x4 acc[4][4] = {};

  for (int k0 = 0; k0 < K; k0 += BK) {
    __syncthreads();
#pragma unroll
    for (int i = 0; i < 2; ++i) {
      int chunk = tid + 256 * i;       // 512 chunks of 8 bf16
      int row = chunk >> 2, cb = chunk & 3;
      *(bf16x8*)&At[row][cb * 8] =
          *(const bf16x8*)(A + (long)(bm + row) * K + k0 + cb * 8);
      *(bf16x8*)&Bt[row][cb * 8] =
          *(const bf16x8*)(Bm + (long)(bn + row) * K + k0 + cb * 8);
    }
    __syncthreads();

    bf16x8 af[4], bfr[4];
#pragma unroll
    for (int m = 0; m < 4; ++m)
      af[m] = *(const bf16x8*)&At[wr * 64 + m * 16 + l16][lhi * 8];
#pragma unroll
    for (int n = 0; n < 4; ++n)
      bfr[n] = *(const bf16x8*)&Bt[wc * 64 + n * 16 + l16][lhi * 8];
#pragma unroll
    for (int m = 0; m < 4; ++m)
#pragma unroll
      for (int n = 0; n < 4; ++n)
        acc[m][n] = __builtin_amdgcn_mfma_f32_16x16x32_bf16(af[m], bfr[n],
                                                            acc[m][n], 0, 0, 0);
  }

  // epilogue + store (C/D layout: col = lane&15, row = (lane>>4)*4 + reg)
#pragma unroll
  for (int m = 0; m < 4; ++m) {
    int row0 = bm + wr * 64 + m * 16 + lhi * 4;
#pragma unroll
    for (int n = 0; n < 4; ++n) {
      int col = bn + wc * 64 + n * 16 + l16;
#pragma unroll
      for (int r = 0; r < 4; ++r) {
        float v = acc[m][n][r];
        int grow = row0 + r;
        if (EPI == 0) {
          v = v / (qn[grow] * kn[col] + 1e-2f);
        } else {
          v = gelu_exact(v);
        }
        Cc[(long)grow * 1024 + col] = f2bf(v);
      }
    }
  }
}

// ---------------------------------------------------------------------------
// wv[row] = dot(h2[row, 0:1024], w3[0:1024]); one wave per row
__global__ __launch_bounds__(256) void wdot(const ushort* __restrict__ h2,
                                            const float* __restrict__ w3,
                                            float* __restrict__ wv) {
  int row = blockIdx.x * 4 + (threadIdx.x >> 6);
  int lane = threadIdx.x & 63;
  const ushort* hr = h2 + (long)row * LK_;
  float acc = 0.f;
#pragma unroll
  for (int i = 0; i < 2; ++i) {
    int idx = (lane + 64 * i) * 8;
    bf16x8 v = *(const bf16x8*)(hr + idx);
#pragma unroll
    for (int j = 0; j < 8; ++j) acc += bf2f((ushort)v[j]) * w3[idx + j];
  }
#pragma unroll
  for (int off = 32; off > 0; off >>= 1) acc += __shfl_xor(acc, off);
  if (lane == 0) wv[row] = acc;
}

// partial: wraw[b,k] += sum_{q in chunk} wv[b,q] * S[b,q,k]
__global__ __launch_bounds__(256) void gate_partial(const ushort* __restrict__ S,
                                                    const float* __restrict__ wv,
                                                    float* __restrict__ wraw) {
  int b = blockIdx.z;
  int k = blockIdx.x * 256 + threadIdx.x;
  int q0 = blockIdx.y * 128;
  const ushort* Sb = S + (long)b * LQ_ * LK_;
  const float* wb = wv + b * LQ_;
  float acc = 0.f;
#pragma unroll 4
  for (int q = q0; q < q0 + 128; ++q) acc += wb[q] * bf2f(Sb[(long)q * LK_ + k]);
  atomicAdd(&wraw[b * LK_ + k], acc);
}

// out[b,k,c] = value * (1 + tanh(wraw/32)); one float4 per thread
__global__ __launch_bounds__(256) void finalize(const float* __restrict__ value,
                                                const float* __restrict__ wraw,
                                                float* __restrict__ out) {
  long i = (long)blockIdx.x * 256 + threadIdx.x;  // float4 index
  long e = i * 4;
  int row = (int)(e >> 9);  // / 512
  float g = 1.f + tanhf(wraw[row] * (1.f / 32.f));
  float4 v = ((const float4*)value)[i];
  v.x *= g; v.y *= g; v.z *= g; v.w *= g;
  ((float4*)out)[i] = v;
}

// ---------------------------------------------------------------------------
extern "C" void kernel_launch(void* const* d_in, const int* in_sizes, int n_in,
                              void* d_out, int out_size, void* d_ws,
                              size_t ws_size, hipStream_t stream) {
  const float* query = (const float*)d_in[0];
  const float* key   = (const float*)d_in[1];
  const float* value = (const float*)d_in[2];
  const float* w1    = (const float*)d_in[3];
  const float* w2    = (const float*)d_in[4];
  const float* w3    = (const float*)d_in[5];
  float* out = (float*)d_out;

  // workspace layout (bytes)
  const size_t QB_BYTES = (size_t)B_ * LQ_ * C_ * 2;       // 16 MB
  const size_t S_BYTES  = (size_t)B_ * LQ_ * LK_ * 2;      // 32 MB
  const size_t W_BYTES  = (size_t)LK_ * LK_ * 2;           // 2 MB
  const size_t OFF_QB = 0;
  const size_t OFF_KB = OFF_QB + QB_BYTES;
  const size_t OFF_H2 = 0;                                  // reuses QB+KB region
  const size_t OFF_S  = OFF_KB + QB_BYTES;
  const size_t OFF_H1 = OFF_S + S_BYTES;
  const size_t OFF_W1 = OFF_H1 + S_BYTES;
  const size_t OFF_W2 = OFF_W1 + W_BYTES;
  const size_t OFF_QN = OFF_W2 + W_BYTES;
  const size_t OFF_KN = OFF_QN + (size_t)B_ * LQ_ * 4;
  const size_t OFF_WV = OFF_KN + (size_t)B_ * LK_ * 4;
  const size_t OFF_WR = OFF_WV + (size_t)B_ * LQ_ * 4;
  const size_t TOTAL  = OFF_WR + (size_t)B_ * LK_ * 4;
  if (ws_size < TOTAL) return;  // workspace too small; fail visibly

  char* ws = (char*)d_ws;
  ushort* Qb  = (ushort*)(ws + OFF_QB);
  ushort* Kb  = (ushort*)(ws + OFF_KB);
  ushort* S   = (ushort*)(ws + OFF_S);
  ushort* h1  = (ushort*)(ws + OFF_H1);
  ushort* h2  = (ushort*)(ws + OFF_H2);
  ushort* W1b = (ushort*)(ws + OFF_W1);
  ushort* W2b = (ushort*)(ws + OFF_W2);
  float* qn   = (float*)(ws + OFF_QN);
  float* kn   = (float*)(ws + OFF_KN);
  float* wv   = (float*)(ws + OFF_WV);
  float* wraw = (float*)(ws + OFF_WR);

  // 1) prep: bf16 casts + norms
  prep_qk<<<dim3(B_ * LQ_ / 4), 256, 0, stream>>>(query, Qb, qn);
  prep_qk<<<dim3(B_ * LK_ / 4), 256, 0, stream>>>(key, Kb, kn);
  conv_bf16<<<dim3(LK_ * LK_ / 4 / 256), 256, 0, stream>>>(w1, W1b, LK_ * LK_ / 4);
  conv_bf16<<<dim3(LK_ * LK_ / 4 / 256), 256, 0, stream>>>(w2, W2b, LK_ * LK_ / 4);
  hipMemsetAsync(wraw, 0, (size_t)B_ * LK_ * 4, stream);

  // 2) S = (Q K^T) / (|q||k| + 1e-2), bf16
  gemm_nt<0><<<dim3(8, 8, B_), 256, 0, stream>>>(
      Qb, Kb, S, C_, (long)LQ_ * C_, (long)LK_ * C_, (long)LQ_ * LK_, qn, kn);

  // 3) h1 = gelu(S @ W1^T)
  gemm_nt<1><<<dim3(8, 8, B_), 256, 0, stream>>>(
      S, W1b, h1, LK_, (long)LQ_ * LK_, 0L, (long)LQ_ * LK_, nullptr, nullptr);

  // 4) h2 = gelu(h1 @ W2^T)
  gemm_nt<1><<<dim3(8, 8, B_), 256, 0, stream>>>(
      h1, W2b, h2, LK_, (long)LQ_ * LK_, 0L, (long)LQ_ * LK_, nullptr, nullptr);

  // 5) wv = h2 @ w3
  wdot<<<dim3(B_ * LQ_ / 4), 256, 0, stream>>>(h2, w3, wv);

  // 6) wraw[b,k] = sum_q wv[b,q] * S[b,q,k]
  gate_partial<<<dim3(LK_ / 256, LQ_ / 128, B_), 256, 0, stream>>>(S, wv, wraw);

  // 7) out = value * (1 + tanh(wraw/32))
  finalize<<<dim3((size_t)B_ * LK_ * C_ / 4 / 256), 256, 0, stream>>>(value, wraw, out);
}

// Round 2
// 199.702 us; speedup vs baseline: 1.0158x; 1.0158x over previous
//
#include <hip/hip_runtime.h>
#include <hip/hip_bf16.h>

// Problem constants (fixed by the reference)
#define B_  16
#define LQ_ 1024
#define LK_ 1024
#define C_  512

typedef __attribute__((ext_vector_type(4))) float f32x4;
typedef __attribute__((ext_vector_type(8))) short bf16x8;

__device__ __forceinline__ float bf2f(ushort u) {
  union { unsigned int i; float f; } v; v.i = ((unsigned int)u) << 16; return v.f;
}
__device__ __forceinline__ ushort f2bf(float f) {
  union { float f; unsigned int i; } v; v.f = f;
  unsigned int r = v.i + 0x7fffu + ((v.i >> 16) & 1u);
  return (ushort)(r >> 16);
}
__device__ __forceinline__ float gelu_exact(float x) {
  return 0.5f * x * (1.0f + erff(x * 0.70710678118654752f));
}

// async global->LDS, 16B per lane; lds base must be wave-uniform (HW writes
// base + lane*16). Source address is per-lane (this is where the swizzle goes).
__device__ __forceinline__ void gload_lds16(const ushort* g, ushort* l) {
  __builtin_amdgcn_global_load_lds(
      (const __attribute__((address_space(1))) void*)g,
      (__attribute__((address_space(3))) void*)l, 16, 0, 0);
}

// ---------------------------------------------------------------------------
// prep: fp32 row (len 512) -> bf16 row + fp32 L2 norm (of ORIGINAL values)
__global__ __launch_bounds__(256) void prep_qk(const float* __restrict__ x,
                                               ushort* __restrict__ xb,
                                               float* __restrict__ norms) {
  int wid = blockIdx.x * 4 + (threadIdx.x >> 6);
  int lane = threadIdx.x & 63;
  const float* xr = x + (long)wid * C_;
  ushort* xo = xb + (long)wid * C_;
  float ss = 0.f;
#pragma unroll
  for (int i0 = 0; i0 < 2; ++i0) {
    int i = lane * 4 + i0 * 256;
    float4 v = *(const float4*)(xr + i);
    ss += v.x * v.x + v.y * v.y + v.z * v.z + v.w * v.w;
    ushort4 o;
    o.x = f2bf(v.x); o.y = f2bf(v.y); o.z = f2bf(v.z); o.w = f2bf(v.w);
    *(ushort4*)(xo + i) = o;
  }
#pragma unroll
  for (int off = 32; off > 0; off >>= 1) ss += __shfl_xor(ss, off);
  if (lane == 0) norms[wid] = sqrtf(ss);
}

// fp32 -> bf16 elementwise (n4 float4 chunks)
__global__ __launch_bounds__(256) void conv_bf16(const float* __restrict__ x,
                                                 ushort* __restrict__ o, int n4) {
  int i = blockIdx.x * 256 + threadIdx.x;
  if (i < n4) {
    float4 v = *(const float4*)(x + (long)i * 4);
    ushort4 u;
    u.x = f2bf(v.x); u.y = f2bf(v.y); u.z = f2bf(v.z); u.w = f2bf(v.w);
    *(ushort4*)(o + (long)i * 4) = u;
  }
}

// ---------------------------------------------------------------------------
// Batched NT GEMM: C[m,n] = epilogue( sum_k A[m,k]*B[n,k] )
// 128x128 tile, BK=32, 4 waves (2x2 of 64x64), 16x16x32 MFMA.
// Staging: global_load_lds width=16, linear LDS [128][32] per operand.
// Bank-conflict fix: 16B-chunk XOR swizzle cb^=(row>>1)&3 applied to the
// GLOBAL source address (stage) and the ds_read address (fragments) —
// LDS destination stays linear as global_load_lds requires (rule 21).
#define BK 32

template <int EPI>
__global__ __launch_bounds__(256, 2) void gemm_nt(
    const ushort* __restrict__ A, const ushort* __restrict__ Bm,
    ushort* __restrict__ Cc, int K, long sA, long sB, long sC,
    const float* __restrict__ qn, const float* __restrict__ kn) {
  int b = blockIdx.z;
  A += (long)b * sA;
  Bm += (long)b * sB;
  Cc += (long)b * sC;
  const int bm = blockIdx.y * 128, bn = blockIdx.x * 128;

  __shared__ ushort At[128][32];
  __shared__ ushort Bt[128][32];

  int tid = threadIdx.x;
  int lane = tid & 63, w = tid >> 6;
  int wr = w >> 1, wc = w & 1;
  int l16 = lane & 15, lhi = lane >> 4;

  f32x4 acc[4][4] = {};

  // per-lane staging coords (2 issues x 256 threads = 512 chunks of 16B/tile)
  int c0 = tid, c1 = tid + 256;
  int r0 = c0 >> 2, cb0 = (c0 & 3) ^ ((r0 >> 1) & 3);
  int r1 = c1 >> 2, cb1 = (c1 & 3) ^ ((r1 >> 1) & 3);
  int wbase0 = (tid & ~63);        // wave-uniform chunk base, issue 0
  int wbase1 = wbase0 + 256;       // issue 1

  const ushort* Ar0 = A + (long)(bm + r0) * K + cb0 * 8;
  const ushort* Ar1 = A + (long)(bm + r1) * K + cb1 * 8;
  const ushort* Br0 = Bm + (long)(bn + r0) * K + cb0 * 8;
  const ushort* Br1 = Bm + (long)(bn + r1) * K + cb1 * 8;

  for (int k0 = 0; k0 < K; k0 += BK) {
    gload_lds16(Ar0 + k0, &At[0][0] + (size_t)wbase0 * 8);
    gload_lds16(Ar1 + k0, &At[0][0] + (size_t)wbase1 * 8);
    gload_lds16(Br0 + k0, &Bt[0][0] + (size_t)wbase0 * 8);
    gload_lds16(Br1 + k0, &Bt[0][0] + (size_t)wbase1 * 8);
    __syncthreads();  // drains vmcnt -> LDS tile ready

    bf16x8 af[4], bfr[4];
#pragma unroll
    for (int m = 0; m < 4; ++m) {
      int r = wr * 64 + m * 16 + l16;
      af[m] = *(const bf16x8*)&At[r][(lhi ^ ((r >> 1) & 3)) * 8];
    }
#pragma unroll
    for (int n = 0; n < 4; ++n) {
      int r = wc * 64 + n * 16 + l16;
      bfr[n] = *(const bf16x8*)&Bt[r][(lhi ^ ((r >> 1) & 3)) * 8];
    }
#pragma unroll
    for (int m = 0; m < 4; ++m)
#pragma unroll
      for (int n = 0; n < 4; ++n)
        acc[m][n] = __builtin_amdgcn_mfma_f32_16x16x32_bf16(af[m], bfr[n],
                                                            acc[m][n], 0, 0, 0);
    __syncthreads();  // protect LDS before next stage
  }

  // epilogue + store (C/D layout: col = lane&15, row = (lane>>4)*4 + reg)
#pragma unroll
  for (int m = 0; m < 4; ++m) {
    int row0 = bm + wr * 64 + m * 16 + lhi * 4;
#pragma unroll
    for (int n = 0; n < 4; ++n) {
      int col = bn + wc * 64 + n * 16 + l16;
#pragma unroll
      for (int r = 0; r < 4; ++r) {
        float v = acc[m][n][r];
        int grow = row0 + r;
        if (EPI == 0) {
          v = v / (qn[grow] * kn[col] + 1e-2f);
        } else {
          v = gelu_exact(v);
        }
        Cc[(long)grow * 1024 + col] = f2bf(v);
      }
    }
  }
}

// ---------------------------------------------------------------------------
// wv[row] = dot(h2[row, 0:1024], w3[0:1024]); one wave per row
__global__ __launch_bounds__(256) void wdot(const ushort* __restrict__ h2,
                                            const float* __restrict__ w3,
                                            float* __restrict__ wv) {
  int row = blockIdx.x * 4 + (threadIdx.x >> 6);
  int lane = threadIdx.x & 63;
  const ushort* hr = h2 + (long)row * LK_;
  float acc = 0.f;
#pragma unroll
  for (int i = 0; i < 2; ++i) {
    int idx = (lane + 64 * i) * 8;
    bf16x8 v = *(const bf16x8*)(hr + idx);
#pragma unroll
    for (int j = 0; j < 8; ++j) acc += bf2f((ushort)v[j]) * w3[idx + j];
  }
#pragma unroll
  for (int off = 32; off > 0; off >>= 1) acc += __shfl_xor(acc, off);
  if (lane == 0) wv[row] = acc;
}

// partial: wraw[b,k] += sum_{q in chunk} wv[b,q] * S[b,q,k]
__global__ __launch_bounds__(256) void gate_partial(const ushort* __restrict__ S,
                                                    const float* __restrict__ wv,
                                                    float* __restrict__ wraw) {
  int b = blockIdx.z;
  int k = blockIdx.x * 256 + threadIdx.x;
  int q0 = blockIdx.y * 128;
  const ushort* Sb = S + (long)b * LQ_ * LK_;
  const float* wb = wv + b * LQ_;
  float acc = 0.f;
#pragma unroll 4
  for (int q = q0; q < q0 + 128; ++q) acc += wb[q] * bf2f(Sb[(long)q * LK_ + k]);
  atomicAdd(&wraw[b * LK_ + k], acc);
}

// out[b,k,c] = value * (1 + tanh(wraw/32)); one float4 per thread
__global__ __launch_bounds__(256) void finalize(const float* __restrict__ value,
                                                const float* __restrict__ wraw,
                                                float* __restrict__ out) {
  long i = (long)blockIdx.x * 256 + threadIdx.x;  // float4 index
  long e = i * 4;
  int row = (int)(e >> 9);  // / 512
  float g = 1.f + tanhf(wraw[row] * (1.f / 32.f));
  float4 v = ((const float4*)value)[i];
  v.x *= g; v.y *= g; v.z *= g; v.w *= g;
  ((float4*)out)[i] = v;
}

// ---------------------------------------------------------------------------
extern "C" void kernel_launch(void* const* d_in, const int* in_sizes, int n_in,
                              void* d_out, int out_size, void* d_ws,
                              size_t ws_size, hipStream_t stream) {
  const float* query = (const float*)d_in[0];
  const float* key   = (const float*)d_in[1];
  const float* value = (const float*)d_in[2];
  const float* w1    = (const float*)d_in[3];
  const float* w2    = (const float*)d_in[4];
  const float* w3    = (const float*)d_in[5];
  float* out = (float*)d_out;

  // workspace layout (bytes)
  const size_t QB_BYTES = (size_t)B_ * LQ_ * C_ * 2;       // 16 MB
  const size_t S_BYTES  = (size_t)B_ * LQ_ * LK_ * 2;      // 32 MB
  const size_t W_BYTES  = (size_t)LK_ * LK_ * 2;           // 2 MB
  const size_t OFF_QB = 0;
  const size_t OFF_KB = OFF_QB + QB_BYTES;
  const size_t OFF_H2 = 0;                                  // reuses QB+KB region
  const size_t OFF_S  = OFF_KB + QB_BYTES;
  const size_t OFF_H1 = OFF_S + S_BYTES;
  const size_t OFF_W1 = OFF_H1 + S_BYTES;
  const size_t OFF_W2 = OFF_W1 + W_BYTES;
  const size_t OFF_QN = OFF_W2 + W_BYTES;
  const size_t OFF_KN = OFF_QN + (size_t)B_ * LQ_ * 4;
  const size_t OFF_WV = OFF_KN + (size_t)B_ * LK_ * 4;
  const size_t OFF_WR = OFF_WV + (size_t)B_ * LQ_ * 4;
  const size_t TOTAL  = OFF_WR + (size_t)B_ * LK_ * 4;
  if (ws_size < TOTAL) return;  // workspace too small; fail visibly

  char* ws = (char*)d_ws;
  ushort* Qb  = (ushort*)(ws + OFF_QB);
  ushort* Kb  = (ushort*)(ws + OFF_KB);
  ushort* S   = (ushort*)(ws + OFF_S);
  ushort* h1  = (ushort*)(ws + OFF_H1);
  ushort* h2  = (ushort*)(ws + OFF_H2);
  ushort* W1b = (ushort*)(ws + OFF_W1);
  ushort* W2b = (ushort*)(ws + OFF_W2);
  float* qn   = (float*)(ws + OFF_QN);
  float* kn   = (float*)(ws + OFF_KN);
  float* wv   = (float*)(ws + OFF_WV);
  float* wraw = (float*)(ws + OFF_WR);

  // 1) prep: bf16 casts + norms
  prep_qk<<<dim3(B_ * LQ_ / 4), 256, 0, stream>>>(query, Qb, qn);
  prep_qk<<<dim3(B_ * LK_ / 4), 256, 0, stream>>>(key, Kb, kn);
  conv_bf16<<<dim3(LK_ * LK_ / 4 / 256), 256, 0, stream>>>(w1, W1b, LK_ * LK_ / 4);
  conv_bf16<<<dim3(LK_ * LK_ / 4 / 256), 256, 0, stream>>>(w2, W2b, LK_ * LK_ / 4);
  hipMemsetAsync(wraw, 0, (size_t)B_ * LK_ * 4, stream);

  // 2) S = (Q K^T) / (|q||k| + 1e-2), bf16
  gemm_nt<0><<<dim3(8, 8, B_), 256, 0, stream>>>(
      Qb, Kb, S, C_, (long)LQ_ * C_, (long)LK_ * C_, (long)LQ_ * LK_, qn, kn);

  // 3) h1 = gelu(S @ W1^T)
  gemm_nt<1><<<dim3(8, 8, B_), 256, 0, stream>>>(
      S, W1b, h1, LK_, (long)LQ_ * LK_, 0L, (long)LQ_ * LK_, nullptr, nullptr);

  // 4) h2 = gelu(h1 @ W2^T)
  gemm_nt<1><<<dim3(8, 8, B_), 256, 0, stream>>>(
      h1, W2b, h2, LK_, (long)LQ_ * LK_, 0L, (long)LQ_ * LK_, nullptr, nullptr);

  // 5) wv = h2 @ w3
  wdot<<<dim3(B_ * LQ_ / 4), 256, 0, stream>>>(h2, w3, wv);

  // 6) wraw[b,k] = sum_q wv[b,q] * S[b,q,k]
  gate_partial<<<dim3(LK_ / 256, LQ_ / 128, B_), 256, 0, stream>>>(S, wv, wraw);

  // 7) out = value * (1 + tanh(wraw/32))
  finalize<<<dim3((size_t)B_ * LK_ * C_ / 4 / 256), 256, 0, stream>>>(value, wraw, out);
}

// Round 3
// 177.618 us; speedup vs baseline: 1.1421x; 1.1243x over previous
//
#include <hip/hip_runtime.h>
#include <hip/hip_bf16.h>

// Problem constants (fixed by the reference)
#define B_  16
#define LQ_ 1024
#define LK_ 1024
#define C_  512

typedef __attribute__((ext_vector_type(4))) float f32x4;
typedef __attribute__((ext_vector_type(8))) short bf16x8;

__device__ __forceinline__ float bf2f(ushort u) {
  union { unsigned int i; float f; } v; v.i = ((unsigned int)u) << 16; return v.f;
}
__device__ __forceinline__ ushort f2bf(float f) {
  union { float f; unsigned int i; } v; v.f = f;
  unsigned int r = v.i + 0x7fffu + ((v.i >> 16) & 1u);
  return (ushort)(r >> 16);
}
__device__ __forceinline__ float gelu_exact(float x) {
  return 0.5f * x * (1.0f + erff(x * 0.70710678118654752f));
}

// async global->LDS, 16B per lane; lds base must be wave-uniform (HW writes
// base + lane*16). Source address is per-lane (this is where the swizzle goes).
__device__ __forceinline__ void gload_lds16(const ushort* g, ushort* l) {
  __builtin_amdgcn_global_load_lds(
      (const __attribute__((address_space(1))) void*)g,
      (__attribute__((address_space(3))) void*)l, 16, 0, 0);
}

// ---------------------------------------------------------------------------
// prep: fp32 row (len 512) -> bf16 row + fp32 L2 norm (of ORIGINAL values)
__global__ __launch_bounds__(256) void prep_qk(const float* __restrict__ x,
                                               ushort* __restrict__ xb,
                                               float* __restrict__ norms) {
  int wid = blockIdx.x * 4 + (threadIdx.x >> 6);
  int lane = threadIdx.x & 63;
  const float* xr = x + (long)wid * C_;
  ushort* xo = xb + (long)wid * C_;
  float ss = 0.f;
#pragma unroll
  for (int i0 = 0; i0 < 2; ++i0) {
    int i = lane * 4 + i0 * 256;
    float4 v = *(const float4*)(xr + i);
    ss += v.x * v.x + v.y * v.y + v.z * v.z + v.w * v.w;
    ushort4 o;
    o.x = f2bf(v.x); o.y = f2bf(v.y); o.z = f2bf(v.z); o.w = f2bf(v.w);
    *(ushort4*)(xo + i) = o;
  }
#pragma unroll
  for (int off = 32; off > 0; off >>= 1) ss += __shfl_xor(ss, off);
  if (lane == 0) norms[wid] = sqrtf(ss);
}

// fp32 -> bf16 elementwise (n4 float4 chunks)
__global__ __launch_bounds__(256) void conv_bf16(const float* __restrict__ x,
                                                 ushort* __restrict__ o, int n4) {
  int i = blockIdx.x * 256 + threadIdx.x;
  if (i < n4) {
    float4 v = *(const float4*)(x + (long)i * 4);
    ushort4 u;
    u.x = f2bf(v.x); u.y = f2bf(v.y); u.z = f2bf(v.z); u.w = f2bf(v.w);
    *(ushort4*)(o + (long)i * 4) = u;
  }
}

// ---------------------------------------------------------------------------
// Batched NT GEMM: C[m,n] = epilogue( sum_k A[m,k]*B[n,k] )
// 128x128 tile, BK=32, 4 waves (2x2 of 64x64), 16x16x32 MFMA.
// 2-phase pipeline (T3-min): double-buffered LDS; next tile's global_load_lds
// issued BEFORE current tile's compute; single __syncthreads() per K-step
// (its implicit vmcnt(0) waits on prefetch that had the whole compute phase
// in flight). Bank-conflict fix: 16B-chunk XOR swizzle cb^=(row>>1)&3 on the
// GLOBAL source (stage) and the ds_read address; LDS dest stays linear.
// Grid is 1D (1024 blocks) with XCD-aware swizzle (T1): 8 bn-blocks sharing
// an A-panel land on the same XCD's L2.
#define BK 32

template <int EPI>
__global__ __launch_bounds__(256, 2) void gemm_nt(
    const ushort* __restrict__ A, const ushort* __restrict__ Bm,
    ushort* __restrict__ Cc, int K, long sA, long sB, long sC,
    const float* __restrict__ qn, const float* __restrict__ kn) {
  // XCD-aware block swizzle: nwg = 1024, nwg % 8 == 0 -> bijective
  int per = (int)(gridDim.x >> 3);
  int orig = blockIdx.x;
  int id = (orig & 7) * per + (orig >> 3);
  int b = id >> 6;              // 64 blocks per batch (8x8)
  int rtile = id & 63;
  const int bm = (rtile >> 3) * 128, bn = (rtile & 7) * 128;

  A += (long)b * sA;
  Bm += (long)b * sB;
  Cc += (long)b * sC;

  __shared__ ushort At[2][128][32];
  __shared__ ushort Bt[2][128][32];

  int tid = threadIdx.x;
  int lane = tid & 63, w = tid >> 6;
  int wr = w >> 1, wc = w & 1;
  int l16 = lane & 15, lhi = lane >> 4;

  f32x4 acc[4][4] = {};

  // per-lane staging coords (2 issues x 256 threads = 512 chunks of 16B/tile)
  int c0 = tid, c1 = tid + 256;
  int r0 = c0 >> 2, cb0 = (c0 & 3) ^ ((r0 >> 1) & 3);
  int r1 = c1 >> 2, cb1 = (c1 & 3) ^ ((r1 >> 1) & 3);
  int wbase0 = (tid & ~63);        // wave-uniform chunk base, issue 0
  int wbase1 = wbase0 + 256;       // issue 1

  const ushort* Ar0 = A + (long)(bm + r0) * K + cb0 * 8;
  const ushort* Ar1 = A + (long)(bm + r1) * K + cb1 * 8;
  const ushort* Br0 = Bm + (long)(bn + r0) * K + cb0 * 8;
  const ushort* Br1 = Bm + (long)(bn + r1) * K + cb1 * 8;

  const int nt = K / BK;
  // prologue: stage tile 0 into buf 0
  {
    ushort* Ad = &At[0][0][0];
    ushort* Bd = &Bt[0][0][0];
    gload_lds16(Ar0, Ad + (size_t)wbase0 * 8);
    gload_lds16(Ar1, Ad + (size_t)wbase1 * 8);
    gload_lds16(Br0, Bd + (size_t)wbase0 * 8);
    gload_lds16(Br1, Bd + (size_t)wbase1 * 8);
  }
  __syncthreads();

  int cur = 0;
  for (int t = 0; t < nt; ++t) {
    // issue next tile's loads into the other buffer BEFORE compute
    if (t + 1 < nt) {
      int k1 = (t + 1) * BK;
      ushort* Ad = &At[cur ^ 1][0][0];
      ushort* Bd = &Bt[cur ^ 1][0][0];
      gload_lds16(Ar0 + k1, Ad + (size_t)wbase0 * 8);
      gload_lds16(Ar1 + k1, Ad + (size_t)wbase1 * 8);
      gload_lds16(Br0 + k1, Bd + (size_t)wbase0 * 8);
      gload_lds16(Br1 + k1, Bd + (size_t)wbase1 * 8);
    }

    bf16x8 af[4], bfr[4];
#pragma unroll
    for (int m = 0; m < 4; ++m) {
      int r = wr * 64 + m * 16 + l16;
      af[m] = *(const bf16x8*)&At[cur][r][(lhi ^ ((r >> 1) & 3)) * 8];
    }
#pragma unroll
    for (int n = 0; n < 4; ++n) {
      int r = wc * 64 + n * 16 + l16;
      bfr[n] = *(const bf16x8*)&Bt[cur][r][(lhi ^ ((r >> 1) & 3)) * 8];
    }
#pragma unroll
    for (int m = 0; m < 4; ++m)
#pragma unroll
      for (int n = 0; n < 4; ++n)
        acc[m][n] = __builtin_amdgcn_mfma_f32_16x16x32_bf16(af[m], bfr[n],
                                                            acc[m][n], 0, 0, 0);
    // implicit vmcnt(0)+lgkmcnt(0) before barrier: waits on the PREFETCH,
    // which has had the whole compute phase in flight; also makes buf[cur]
    // safe to overwrite next iteration.
    __syncthreads();
    cur ^= 1;
  }

  // epilogue + store (C/D layout: col = lane&15, row = (lane>>4)*4 + reg)
#pragma unroll
  for (int m = 0; m < 4; ++m) {
    int row0 = bm + wr * 64 + m * 16 + lhi * 4;
#pragma unroll
    for (int n = 0; n < 4; ++n) {
      int col = bn + wc * 64 + n * 16 + l16;
#pragma unroll
      for (int r = 0; r < 4; ++r) {
        float v = acc[m][n][r];
        int grow = row0 + r;
        if (EPI == 0) {
          v = v / (qn[grow] * kn[col] + 1e-2f);
        } else {
          v = gelu_exact(v);
        }
        Cc[(long)grow * 1024 + col] = f2bf(v);
      }
    }
  }
}

// ---------------------------------------------------------------------------
// wv[row] = dot(h2[row, 0:1024], w3[0:1024]); one wave per row
__global__ __launch_bounds__(256) void wdot(const ushort* __restrict__ h2,
                                            const float* __restrict__ w3,
                                            float* __restrict__ wv) {
  int row = blockIdx.x * 4 + (threadIdx.x >> 6);
  int lane = threadIdx.x & 63;
  const ushort* hr = h2 + (long)row * LK_;
  float acc = 0.f;
#pragma unroll
  for (int i = 0; i < 2; ++i) {
    int idx = (lane + 64 * i) * 8;
    bf16x8 v = *(const bf16x8*)(hr + idx);
#pragma unroll
    for (int j = 0; j < 8; ++j) acc += bf2f((ushort)v[j]) * w3[idx + j];
  }
#pragma unroll
  for (int off = 32; off > 0; off >>= 1) acc += __shfl_xor(acc, off);
  if (lane == 0) wv[row] = acc;
}

// partial: wraw[b,k] += sum_{q in chunk} wv[b,q] * S[b,q,k]
__global__ __launch_bounds__(256) void gate_partial(const ushort* __restrict__ S,
                                                    const float* __restrict__ wv,
                                                    float* __restrict__ wraw) {
  int b = blockIdx.z;
  int k = blockIdx.x * 256 + threadIdx.x;
  int q0 = blockIdx.y * 128;
  const ushort* Sb = S + (long)b * LQ_ * LK_;
  const float* wb = wv + b * LQ_;
  float acc = 0.f;
#pragma unroll 4
  for (int q = q0; q < q0 + 128; ++q) acc += wb[q] * bf2f(Sb[(long)q * LK_ + k]);
  atomicAdd(&wraw[b * LK_ + k], acc);
}

// out[b,k,c] = value * (1 + tanh(wraw/32)); one float4 per thread
__global__ __launch_bounds__(256) void finalize(const float* __restrict__ value,
                                                const float* __restrict__ wraw,
                                                float* __restrict__ out) {
  long i = (long)blockIdx.x * 256 + threadIdx.x;  // float4 index
  long e = i * 4;
  int row = (int)(e >> 9);  // / 512
  float g = 1.f + tanhf(wraw[row] * (1.f / 32.f));
  float4 v = ((const float4*)value)[i];
  v.x *= g; v.y *= g; v.z *= g; v.w *= g;
  ((float4*)out)[i] = v;
}

// ---------------------------------------------------------------------------
extern "C" void kernel_launch(void* const* d_in, const int* in_sizes, int n_in,
                              void* d_out, int out_size, void* d_ws,
                              size_t ws_size, hipStream_t stream) {
  const float* query = (const float*)d_in[0];
  const float* key   = (const float*)d_in[1];
  const float* value = (const float*)d_in[2];
  const float* w1    = (const float*)d_in[3];
  const float* w2    = (const float*)d_in[4];
  const float* w3    = (const float*)d_in[5];
  float* out = (float*)d_out;

  // workspace layout (bytes)
  const size_t QB_BYTES = (size_t)B_ * LQ_ * C_ * 2;       // 16 MB
  const size_t S_BYTES  = (size_t)B_ * LQ_ * LK_ * 2;      // 32 MB
  const size_t W_BYTES  = (size_t)LK_ * LK_ * 2;           // 2 MB
  const size_t OFF_QB = 0;
  const size_t OFF_KB = OFF_QB + QB_BYTES;
  const size_t OFF_H2 = 0;                                  // reuses QB+KB region
  const size_t OFF_S  = OFF_KB + QB_BYTES;
  const size_t OFF_H1 = OFF_S + S_BYTES;
  const size_t OFF_W1 = OFF_H1 + S_BYTES;
  const size_t OFF_W2 = OFF_W1 + W_BYTES;
  const size_t OFF_QN = OFF_W2 + W_BYTES;
  const size_t OFF_KN = OFF_QN + (size_t)B_ * LQ_ * 4;
  const size_t OFF_WV = OFF_KN + (size_t)B_ * LK_ * 4;
  const size_t OFF_WR = OFF_WV + (size_t)B_ * LQ_ * 4;
  const size_t TOTAL  = OFF_WR + (size_t)B_ * LK_ * 4;
  if (ws_size < TOTAL) return;  // workspace too small; fail visibly

  char* ws = (char*)d_ws;
  ushort* Qb  = (ushort*)(ws + OFF_QB);
  ushort* Kb  = (ushort*)(ws + OFF_KB);
  ushort* S   = (ushort*)(ws + OFF_S);
  ushort* h1  = (ushort*)(ws + OFF_H1);
  ushort* h2  = (ushort*)(ws + OFF_H2);
  ushort* W1b = (ushort*)(ws + OFF_W1);
  ushort* W2b = (ushort*)(ws + OFF_W2);
  float* qn   = (float*)(ws + OFF_QN);
  float* kn   = (float*)(ws + OFF_KN);
  float* wv   = (float*)(ws + OFF_WV);
  float* wraw = (float*)(ws + OFF_WR);

  // 1) prep: bf16 casts + norms
  prep_qk<<<dim3(B_ * LQ_ / 4), 256, 0, stream>>>(query, Qb, qn);
  prep_qk<<<dim3(B_ * LK_ / 4), 256, 0, stream>>>(key, Kb, kn);
  conv_bf16<<<dim3(LK_ * LK_ / 4 / 256), 256, 0, stream>>>(w1, W1b, LK_ * LK_ / 4);
  conv_bf16<<<dim3(LK_ * LK_ / 4 / 256), 256, 0, stream>>>(w2, W2b, LK_ * LK_ / 4);
  hipMemsetAsync(wraw, 0, (size_t)B_ * LK_ * 4, stream);

  // 2) S = (Q K^T) / (|q||k| + 1e-2), bf16
  gemm_nt<0><<<dim3(1024), 256, 0, stream>>>(
      Qb, Kb, S, C_, (long)LQ_ * C_, (long)LK_ * C_, (long)LQ_ * LK_, qn, kn);

  // 3) h1 = gelu(S @ W1^T)
  gemm_nt<1><<<dim3(1024), 256, 0, stream>>>(
      S, W1b, h1, LK_, (long)LQ_ * LK_, 0L, (long)LQ_ * LK_, nullptr, nullptr);

  // 4) h2 = gelu(h1 @ W2^T)
  gemm_nt<1><<<dim3(1024), 256, 0, stream>>>(
      h1, W2b, h2, LK_, (long)LQ_ * LK_, 0L, (long)LQ_ * LK_, nullptr, nullptr);

  // 5) wv = h2 @ w3
  wdot<<<dim3(B_ * LQ_ / 4), 256, 0, stream>>>(h2, w3, wv);

  // 6) wraw[b,k] = sum_q wv[b,q] * S[b,q,k]
  gate_partial<<<dim3(LK_ / 256, LQ_ / 128, B_), 256, 0, stream>>>(S, wv, wraw);

  // 7) out = value * (1 + tanh(wraw/32))
  finalize<<<dim3((size_t)B_ * LK_ * C_ / 4 / 256), 256, 0, stream>>>(value, wraw, out);
}

// Round 4
// 170.167 us; speedup vs baseline: 1.1921x; 1.0438x over previous
//
#include <hip/hip_runtime.h>
#include <hip/hip_bf16.h>

// Problem constants (fixed by the reference)
#define B_  16
#define LQ_ 1024
#define LK_ 1024
#define C_  512

typedef __attribute__((ext_vector_type(4))) float f32x4;
typedef __attribute__((ext_vector_type(8))) short bf16x8;

__device__ __forceinline__ float bf2f(ushort u) {
  union { unsigned int i; float f; } v; v.i = ((unsigned int)u) << 16; return v.f;
}
__device__ __forceinline__ ushort f2bf(float f) {
  union { float f; unsigned int i; } v; v.f = f;
  unsigned int r = v.i + 0x7fffu + ((v.i >> 16) & 1u);
  return (ushort)(r >> 16);
}
__device__ __forceinline__ float gelu_exact(float x) {
  return 0.5f * x * (1.0f + erff(x * 0.70710678118654752f));
}

// async global->LDS, 16B per lane; LDS dest is wave-uniform base + lane*16.
__device__ __forceinline__ void gload_lds16(const ushort* g, ushort* l) {
  __builtin_amdgcn_global_load_lds(
      (const __attribute__((address_space(1))) void*)g,
      (__attribute__((address_space(3))) void*)l, 16, 0, 0);
}

// ---------------------------------------------------------------------------
// prep: fp32 row (len 512) -> bf16 row + fp32 L2 norm (of ORIGINAL values)
__global__ __launch_bounds__(256) void prep_qk(const float* __restrict__ x,
                                               ushort* __restrict__ xb,
                                               float* __restrict__ norms) {
  int wid = blockIdx.x * 4 + (threadIdx.x >> 6);
  int lane = threadIdx.x & 63;
  const float* xr = x + (long)wid * C_;
  ushort* xo = xb + (long)wid * C_;
  float ss = 0.f;
#pragma unroll
  for (int i0 = 0; i0 < 2; ++i0) {
    int i = lane * 4 + i0 * 256;
    float4 v = *(const float4*)(xr + i);
    ss += v.x * v.x + v.y * v.y + v.z * v.z + v.w * v.w;
    ushort4 o;
    o.x = f2bf(v.x); o.y = f2bf(v.y); o.z = f2bf(v.z); o.w = f2bf(v.w);
    *(ushort4*)(xo + i) = o;
  }
#pragma unroll
  for (int off = 32; off > 0; off >>= 1) ss += __shfl_xor(ss, off);
  if (lane == 0) norms[wid] = sqrtf(ss);
}

// fp32 -> bf16 elementwise (n4 float4 chunks)
__global__ __launch_bounds__(256) void conv_bf16(const float* __restrict__ x,
                                                 ushort* __restrict__ o, int n4) {
  int i = blockIdx.x * 256 + threadIdx.x;
  if (i < n4) {
    float4 v = *(const float4*)(x + (long)i * 4);
    ushort4 u;
    u.x = f2bf(v.x); u.y = f2bf(v.y); u.z = f2bf(v.z); u.w = f2bf(v.w);
    *(ushort4*)(o + (long)i * 4) = u;
  }
}

// ---------------------------------------------------------------------------
// Batched NT GEMM, 256x256 tile, BK=64, 512 threads = 8 waves (2M x 4N),
// per-wave output 128x64. Multi-phase schedule (T3+T4+T5):
//   per K-tile, 4 phases: {ds_read frag subtile; issue staging for t+1;
//   s_barrier; setprio(1); 16 MFMA; setprio(0); s_barrier}
//   staging spread over phases 0-2; single s_waitcnt vmcnt(0) at end of
//   phase 3 (prefetch had ~the whole tile in flight). Raw s_barrier -> no
//   implicit vmcnt(0) drains mid-tile.
// LDS: linear [2][256][64] per operand (128 KiB total), chunk-XOR swizzle
// cb ^= (row&7) applied to the GLOBAL source (stage) and ds_read address —
// uniform 8 lanes per 16B slot => conflict-free b128 (verified 0 conflicts
// with the same scheme in R2/R3).
// EPI 0: v/(qn*kn+1e-2) -> bf16 C.  EPI 1: exact gelu -> bf16 C.
// EPI 2: no C store; fused row-dot with w3 -> atomicAdd into wv.
template <int EPI>
__global__ __launch_bounds__(512, 2) void gemm256(
    const ushort* __restrict__ A, const ushort* __restrict__ Bm,
    ushort* __restrict__ Cc, int K, long sA, long sB, long sC,
    const float* __restrict__ qn, const float* __restrict__ kn,
    const float* __restrict__ w3v, float* __restrict__ wv) {
  // XCD-aware block swizzle: grid = 256, 256 % 8 == 0 -> bijective
  int per = (int)(gridDim.x >> 3);
  int orig = blockIdx.x;
  int id = (orig & 7) * per + (orig >> 3);
  int b = id >> 4;              // 16 tiles per batch (4x4)
  int rt = id & 15;
  const int bm = (rt >> 2) * 256, bn = (rt & 3) * 256;

  A += (long)b * sA;
  Bm += (long)b * sB;

  __shared__ ushort At[2][256][64];
  __shared__ ushort Bt[2][256][64];
  const int bufStride = 256 * 64;  // ushorts per buffer

  const int tid = threadIdx.x;
  const int lane = tid & 63, w = tid >> 6;
  const int wr = w >> 2, wc = w & 3;          // 2 x 4 wave grid
  const int l16 = lane & 15, lhi = lane >> 4;

  f32x4 acc[8][4] = {};

  // staging: 2048 chunks (16B) per operand per K-tile; 4 issues x 512 thr.
  // LDS chunk c holds global logical chunk (c&7) ^ (row&7).
  const ushort* gA[4];
  const ushort* gB[4];
  ushort* lA[4];
  ushort* lB[4];
#pragma unroll
  for (int i = 0; i < 4; ++i) {
    int c = i * 512 + tid;
    int row = c >> 3;
    int cb = (c & 7) ^ (row & 7);
    gA[i] = A + (long)(bm + row) * K + cb * 8;
    gB[i] = Bm + (long)(bn + row) * K + cb * 8;
    int wch = i * 512 + (tid & ~63);  // wave-uniform chunk base
    lA[i] = &At[0][0][0] + (size_t)wch * 8;
    lB[i] = &Bt[0][0][0] + (size_t)wch * 8;
  }

  // prologue: stage tile 0 into buf 0
#pragma unroll
  for (int i = 0; i < 4; ++i) {
    gload_lds16(gA[i], lA[i]);
    gload_lds16(gB[i], lB[i]);
  }
  asm volatile("s_waitcnt vmcnt(0)" ::: "memory");
  __builtin_amdgcn_s_barrier();

  const int nt = K / 64;
  int cur = 0;
  for (int t = 0; t < nt; ++t) {
    const int koff = (t + 1) * 64;
    const bool pf = (t + 1 < nt);
    const ushort* Acur = &At[cur][0][0];
    const ushort* Bcur = &Bt[cur][0][0];
    const size_t nxo = (size_t)(cur ^ 1) * bufStride;

    bf16x8 bfr[4][2];  // B fragments for the whole K-tile (loaded phase 0)

#pragma unroll
    for (int p = 0; p < 4; ++p) {
      // ds-read this phase's A fragment subtile (m-pair 2p, 2p+1)
      bf16x8 af[2][2];
#pragma unroll
      for (int e = 0; e < 2; ++e)
#pragma unroll
        for (int kk = 0; kk < 2; ++kk) {
          int r = wr * 128 + (p * 2 + e) * 16 + l16;
          af[e][kk] = *(const bf16x8*)(Acur + r * 64 +
                                       (((kk * 4 + lhi) ^ (r & 7)) * 8));
        }
      if (p == 0) {
#pragma unroll
        for (int n = 0; n < 4; ++n)
#pragma unroll
          for (int kk = 0; kk < 2; ++kk) {
            int r = wc * 64 + n * 16 + l16;
            bfr[n][kk] = *(const bf16x8*)(Bcur + r * 64 +
                                          (((kk * 4 + lhi) ^ (r & 7)) * 8));
          }
      }
      // issue next tile's staging (spread over phases 0-2)
      if (pf) {
        if (p == 0) {
          gload_lds16(gA[0] + koff, lA[0] + nxo);
          gload_lds16(gA[1] + koff, lA[1] + nxo);
          gload_lds16(gB[0] + koff, lB[0] + nxo);
        } else if (p == 1) {
          gload_lds16(gA[2] + koff, lA[2] + nxo);
          gload_lds16(gA[3] + koff, lA[3] + nxo);
          gload_lds16(gB[1] + koff, lB[1] + nxo);
        } else if (p == 2) {
          gload_lds16(gB[2] + koff, lB[2] + nxo);
          gload_lds16(gB[3] + koff, lB[3] + nxo);
        }
      }
      __builtin_amdgcn_s_barrier();
      __builtin_amdgcn_s_setprio(1);
#pragma unroll
      for (int e = 0; e < 2; ++e)
#pragma unroll
        for (int n = 0; n < 4; ++n)
#pragma unroll
          for (int kk = 0; kk < 2; ++kk)
            acc[p * 2 + e][n] = __builtin_amdgcn_mfma_f32_16x16x32_bf16(
                af[e][kk], bfr[n][kk], acc[p * 2 + e][n], 0, 0, 0);
      __builtin_amdgcn_s_setprio(0);
      if (p == 3) asm volatile("s_waitcnt vmcnt(0)" ::: "memory");
      __builtin_amdgcn_s_barrier();
    }
    cur ^= 1;
  }

  // epilogue (C/D layout: col = lane&15, row = (lane>>4)*4 + reg)
  if constexpr (EPI == 2) {
    float* wvb = wv + (long)b * LQ_;
    float w3c[4];
#pragma unroll
    for (int n = 0; n < 4; ++n) w3c[n] = w3v[bn + wc * 64 + n * 16 + l16];
#pragma unroll
    for (int m = 0; m < 8; ++m)
#pragma unroll
      for (int rr = 0; rr < 4; ++rr) {
        float s = 0.f;
#pragma unroll
        for (int n = 0; n < 4; ++n)
          s += gelu_exact(acc[m][n][rr]) * w3c[n];
        s += __shfl_xor(s, 1);
        s += __shfl_xor(s, 2);
        s += __shfl_xor(s, 4);
        s += __shfl_xor(s, 8);
        if (l16 == 0)
          atomicAdd(&wvb[bm + wr * 128 + m * 16 + lhi * 4 + rr], s);
      }
  } else {
    Cc += (long)b * sC;
    const float* qnb = qn + (long)b * LQ_;
    const float* knb = kn + (long)b * LK_;
#pragma unroll
    for (int m = 0; m < 8; ++m) {
      int row0 = bm + wr * 128 + m * 16 + lhi * 4;
#pragma unroll
      for (int n = 0; n < 4; ++n) {
        int col = bn + wc * 64 + n * 16 + l16;
#pragma unroll
        for (int rr = 0; rr < 4; ++rr) {
          float v = acc[m][n][rr];
          int grow = row0 + rr;
          if (EPI == 0) {
            v = v / (qnb[grow] * knb[col] + 1e-2f);
          } else {
            v = gelu_exact(v);
          }
          Cc[(long)grow * 1024 + col] = f2bf(v);
        }
      }
    }
  }
}

// ---------------------------------------------------------------------------
// partial: wraw[b,k] += sum_{q in chunk} wv[b,q] * S[b,q,k]
__global__ __launch_bounds__(256) void gate_partial(const ushort* __restrict__ S,
                                                    const float* __restrict__ wv,
                                                    float* __restrict__ wraw) {
  int b = blockIdx.z;
  int k = blockIdx.x * 256 + threadIdx.x;
  int q0 = blockIdx.y * 128;
  const ushort* Sb = S + (long)b * LQ_ * LK_;
  const float* wb = wv + b * LQ_;
  float acc = 0.f;
#pragma unroll 4
  for (int q = q0; q < q0 + 128; ++q) acc += wb[q] * bf2f(Sb[(long)q * LK_ + k]);
  atomicAdd(&wraw[b * LK_ + k], acc);
}

// out[b,k,c] = value * (1 + tanh(wraw/32)); one float4 per thread
__global__ __launch_bounds__(256) void finalize(const float* __restrict__ value,
                                                const float* __restrict__ wraw,
                                                float* __restrict__ out) {
  long i = (long)blockIdx.x * 256 + threadIdx.x;  // float4 index
  long e = i * 4;
  int row = (int)(e >> 9);  // / 512
  float g = 1.f + tanhf(wraw[row] * (1.f / 32.f));
  float4 v = ((const float4*)value)[i];
  v.x *= g; v.y *= g; v.z *= g; v.w *= g;
  ((float4*)out)[i] = v;
}

// ---------------------------------------------------------------------------
extern "C" void kernel_launch(void* const* d_in, const int* in_sizes, int n_in,
                              void* d_out, int out_size, void* d_ws,
                              size_t ws_size, hipStream_t stream) {
  const float* query = (const float*)d_in[0];
  const float* key   = (const float*)d_in[1];
  const float* value = (const float*)d_in[2];
  const float* w1    = (const float*)d_in[3];
  const float* w2    = (const float*)d_in[4];
  const float* w3    = (const float*)d_in[5];
  float* out = (float*)d_out;

  // workspace layout (bytes)
  const size_t QB_BYTES = (size_t)B_ * LQ_ * C_ * 2;       // 16 MB
  const size_t S_BYTES  = (size_t)B_ * LQ_ * LK_ * 2;      // 32 MB
  const size_t W_BYTES  = (size_t)LK_ * LK_ * 2;           // 2 MB
  const size_t OFF_QB = 0;
  const size_t OFF_KB = OFF_QB + QB_BYTES;
  const size_t OFF_S  = OFF_KB + QB_BYTES;
  const size_t OFF_H1 = OFF_S + S_BYTES;
  const size_t OFF_W1 = OFF_H1 + S_BYTES;
  const size_t OFF_W2 = OFF_W1 + W_BYTES;
  const size_t OFF_QN = OFF_W2 + W_BYTES;
  const size_t OFF_KN = OFF_QN + (size_t)B_ * LQ_ * 4;
  const size_t OFF_WV = OFF_KN + (size_t)B_ * LK_ * 4;
  const size_t OFF_WR = OFF_WV + (size_t)B_ * LQ_ * 4;
  const size_t TOTAL  = OFF_WR + (size_t)B_ * LK_ * 4;
  if (ws_size < TOTAL) return;  // workspace too small; fail visibly

  char* ws = (char*)d_ws;
  ushort* Qb  = (ushort*)(ws + OFF_QB);
  ushort* Kb  = (ushort*)(ws + OFF_KB);
  ushort* S   = (ushort*)(ws + OFF_S);
  ushort* h1  = (ushort*)(ws + OFF_H1);
  ushort* W1b = (ushort*)(ws + OFF_W1);
  ushort* W2b = (ushort*)(ws + OFF_W2);
  float* qn   = (float*)(ws + OFF_QN);
  float* kn   = (float*)(ws + OFF_KN);
  float* wv   = (float*)(ws + OFF_WV);
  float* wraw = (float*)(ws + OFF_WR);

  // 1) prep: bf16 casts + norms
  prep_qk<<<dim3(B_ * LQ_ / 4), 256, 0, stream>>>(query, Qb, qn);
  prep_qk<<<dim3(B_ * LK_ / 4), 256, 0, stream>>>(key, Kb, kn);
  conv_bf16<<<dim3(LK_ * LK_ / 4 / 256), 256, 0, stream>>>(w1, W1b, LK_ * LK_ / 4);
  conv_bf16<<<dim3(LK_ * LK_ / 4 / 256), 256, 0, stream>>>(w2, W2b, LK_ * LK_ / 4);
  hipMemsetAsync(wraw, 0, (size_t)B_ * LK_ * 4, stream);
  hipMemsetAsync(wv, 0, (size_t)B_ * LQ_ * 4, stream);

  // 2) S = (Q K^T) / (|q||k| + 1e-2), bf16
  gemm256<0><<<dim3(256), 512, 0, stream>>>(
      Qb, Kb, S, C_, (long)LQ_ * C_, (long)LK_ * C_, (long)LQ_ * LK_,
      qn, kn, nullptr, nullptr);

  // 3) h1 = gelu(S @ W1^T)
  gemm256<1><<<dim3(256), 512, 0, stream>>>(
      S, W1b, h1, LK_, (long)LQ_ * LK_, 0L, (long)LQ_ * LK_,
      nullptr, nullptr, nullptr, nullptr);

  // 4) fused: wv[b,q] = dot(gelu(h1 @ W2^T)[q,:], w3)  (h2 never stored)
  gemm256<2><<<dim3(256), 512, 0, stream>>>(
      h1, W2b, nullptr, LK_, (long)LQ_ * LK_, 0L, 0L,
      nullptr, nullptr, w3, wv);

  // 5) wraw[b,k] = sum_q wv[b,q] * S[b,q,k]
  gate_partial<<<dim3(LK_ / 256, LQ_ / 128, B_), 256, 0, stream>>>(S, wv, wraw);

  // 6) out = value * (1 + tanh(wraw/32))
  finalize<<<dim3((size_t)B_ * LK_ * C_ / 4 / 256), 256, 0, stream>>>(value, wraw, out);
}

// Round 5
// 166.181 us; speedup vs baseline: 1.2207x; 1.0240x over previous
//
#include <hip/hip_runtime.h>
#include <hip/hip_bf16.h>

// Problem constants (fixed by the reference)
#define B_  16
#define LQ_ 1024
#define LK_ 1024
#define C_  512

typedef __attribute__((ext_vector_type(4))) float f32x4;
typedef __attribute__((ext_vector_type(8))) short bf16x8;

__device__ __forceinline__ float bf2f(ushort u) {
  union { unsigned int i; float f; } v; v.i = ((unsigned int)u) << 16; return v.f;
}
__device__ __forceinline__ ushort f2bf(float f) {
  union { float f; unsigned int i; } v; v.f = f;
  unsigned int r = v.i + 0x7fffu + ((v.i >> 16) & 1u);
  return (ushort)(r >> 16);
}
__device__ __forceinline__ float gelu_exact(float x) {
  return 0.5f * x * (1.0f + erff(x * 0.70710678118654752f));
}

// async global->LDS, 16B per lane; LDS dest is wave-uniform base + lane*16.
__device__ __forceinline__ void gload_lds16(const ushort* g, ushort* l) {
  __builtin_amdgcn_global_load_lds(
      (const __attribute__((address_space(1))) void*)g,
      (__attribute__((address_space(3))) void*)l, 16, 0, 0);
}

// ---------------------------------------------------------------------------
// prep: fp32 row (len 512) -> bf16 row + fp32 L2 norm (of ORIGINAL values)
__global__ __launch_bounds__(256) void prep_qk(const float* __restrict__ x,
                                               ushort* __restrict__ xb,
                                               float* __restrict__ norms) {
  int wid = blockIdx.x * 4 + (threadIdx.x >> 6);
  int lane = threadIdx.x & 63;
  const float* xr = x + (long)wid * C_;
  ushort* xo = xb + (long)wid * C_;
  float ss = 0.f;
#pragma unroll
  for (int i0 = 0; i0 < 2; ++i0) {
    int i = lane * 4 + i0 * 256;
    float4 v = *(const float4*)(xr + i);
    ss += v.x * v.x + v.y * v.y + v.z * v.z + v.w * v.w;
    ushort4 o;
    o.x = f2bf(v.x); o.y = f2bf(v.y); o.z = f2bf(v.z); o.w = f2bf(v.w);
    *(ushort4*)(xo + i) = o;
  }
#pragma unroll
  for (int off = 32; off > 0; off >>= 1) ss += __shfl_xor(ss, off);
  if (lane == 0) norms[wid] = sqrtf(ss);
}

// fp32 -> bf16 elementwise (n4 float4 chunks)
__global__ __launch_bounds__(256) void conv_bf16(const float* __restrict__ x,
                                                 ushort* __restrict__ o, int n4) {
  int i = blockIdx.x * 256 + threadIdx.x;
  if (i < n4) {
    float4 v = *(const float4*)(x + (long)i * 4);
    ushort4 u;
    u.x = f2bf(v.x); u.y = f2bf(v.y); u.z = f2bf(v.z); u.w = f2bf(v.w);
    *(ushort4*)(o + (long)i * 4) = u;
  }
}

// ---------------------------------------------------------------------------
// Batched NT GEMM, 256x256 tile, BK=64, 512 threads = 8 waves (2M x 4N).
// Counted-vmcnt pipeline (T3+T4+T5):
//   4 phases per K-tile = C-quadrants (mh,nh): p0 reads A-mh0 + B-nh0 frags,
//   p1 reads B-nh1, p2 reads A-mh1, p3 reads nothing (regs). Staging of tile
//   t+1 split into 8 single-gload slots, 2 per phase: p0:{A0,A2} p1:{B0,B1}
//   p2:{B2,B3} p3:{A1,A3}. Uniform `s_waitcnt vmcnt(4)` before each phase's
//   single s_barrier guarantees the NEXT phase's ds_read data (each slot gets
//   >=3 phases of latency hiding; never drains to 0 in the main loop).
// B's LDS rows remapped l = nh*128 + wc*32 + ni*16 + l16 so each gload slot
// (64 LDS rows) feeds exactly one consuming phase.
// 16B-chunk XOR swizzle j = g ^ (l&7) on global source + ds_read address;
// LDS dest linear (rule 21). Conflict-free per 16-lane group (measured 0).
// EPI 0: v/(qn*kn+1e-2) -> bf16 C.  EPI 1: exact gelu -> bf16 C.
// EPI 2: no C store; fused row-dot with w3 -> atomicAdd into wv.
template <int EPI>
__global__ __launch_bounds__(512, 2) void gemm256(
    const ushort* __restrict__ A, const ushort* __restrict__ Bm,
    ushort* __restrict__ Cc, int K, long sA, long sB, long sC,
    const float* __restrict__ qn, const float* __restrict__ kn,
    const float* __restrict__ w3v, float* __restrict__ wv) {
  // XCD-aware block swizzle: grid = 256, 256 % 8 == 0 -> bijective
  int per = (int)(gridDim.x >> 3);
  int orig = blockIdx.x;
  int id = (orig & 7) * per + (orig >> 3);
  int b = id >> 4;              // 16 tiles per batch (4x4)
  int rt = id & 15;
  const int bm = (rt >> 2) * 256, bn = (rt & 3) * 256;

  A += (long)b * sA + (long)bm * K;   // fold bm into A base
  Bm += (long)b * sB;

  __shared__ ushort At[2][256 * 64];
  __shared__ ushort Bt[2][256 * 64];

  const int tid = threadIdx.x;
  const int lane = tid & 63, w = tid >> 6;
  const int wr = w >> 2, wc = w & 3;          // 2 x 4 wave grid
  const int l16 = lane & 15, lhi = lane >> 4;

  f32x4 acc[8][4] = {};

  // staging slots: slot s covers LDS rows [s*64, s*64+64) of one operand.
  const ushort* gAs[4];
  const ushort* gBs[4];
  int dstc[4];
#pragma unroll
  for (int s = 0; s < 4; ++s) {
    int c = s * 512 + tid;          // global chunk index (16B units)
    int l = c >> 3;                 // LDS row
    int cb = (c & 7) ^ (l & 7);     // swizzled source column chunk
    gAs[s] = A + (long)l * K + cb * 8;
    int nh = l >> 7, wcb = (l >> 5) & 3, jj = l & 31;
    int rb = wcb * 64 + nh * 32 + jj;   // global B row for LDS row l
    gBs[s] = Bm + (long)(bn + rb) * K + cb * 8;
    dstc[s] = (s * 512 + (tid & ~63)) * 8;  // ushort offset (wave-uniform)
  }

  // prologue: stage tile 0, order A0,A2,B0,B1,B2,B3,A1,A3
  {
    ushort* Ad = &At[0][0];
    ushort* Bd = &Bt[0][0];
    gload_lds16(gAs[0], Ad + dstc[0]);
    gload_lds16(gAs[2], Ad + dstc[2]);
    gload_lds16(gBs[0], Bd + dstc[0]);
    gload_lds16(gBs[1], Bd + dstc[1]);
    gload_lds16(gBs[2], Bd + dstc[2]);
    gload_lds16(gBs[3], Bd + dstc[3]);
    gload_lds16(gAs[1], Ad + dstc[1]);
    gload_lds16(gAs[3], Ad + dstc[3]);
  }
  asm volatile("s_waitcnt vmcnt(4)" ::: "memory");
  __builtin_amdgcn_s_barrier();

  const int xk0 = (lhi ^ (l16 & 7)) * 8;
  const int xk1 = ((4 + lhi) ^ (l16 & 7)) * 8;

#define MFMA_QUAD(MH, NH, BB)                                              \
  __builtin_amdgcn_s_setprio(1);                                           \
  _Pragma("unroll") for (int mi = 0; mi < 4; ++mi)                         \
      _Pragma("unroll") for (int ni = 0; ni < 2; ++ni)                     \
          _Pragma("unroll") for (int kk = 0; kk < 2; ++kk)                 \
              acc[(MH)*4 + mi][(NH)*2 + ni] =                              \
      __builtin_amdgcn_mfma_f32_16x16x32_bf16(                             \
          aa[mi][kk], BB[ni][kk], acc[(MH)*4 + mi][(NH)*2 + ni], 0, 0, 0); \
  __builtin_amdgcn_s_setprio(0);

  const int nt = K / 64;
  int cur = 0;
  for (int t = 0; t < nt; ++t) {
    const ushort* Ac = &At[cur][0];
    const ushort* Bc = &Bt[cur][0];
    ushort* Ad = &At[cur ^ 1][0];
    ushort* Bd = &Bt[cur ^ 1][0];
    const int ko = (t + 1) * 64;
    const bool pf = (t + 1 < nt);

    bf16x8 aa[4][2], b0[2][2], b1[2][2];

    // -------- phase 0: quadrant (mh0, nh0)
#pragma unroll
    for (int mi = 0; mi < 4; ++mi) {
      int r = wr * 128 + mi * 16 + l16;
      aa[mi][0] = *(const bf16x8*)(Ac + r * 64 + xk0);
      aa[mi][1] = *(const bf16x8*)(Ac + r * 64 + xk1);
    }
#pragma unroll
    for (int ni = 0; ni < 2; ++ni) {
      int lb = wc * 32 + ni * 16 + l16;
      b0[ni][0] = *(const bf16x8*)(Bc + lb * 64 + xk0);
      b0[ni][1] = *(const bf16x8*)(Bc + lb * 64 + xk1);
    }
    if (pf) {
      gload_lds16(gAs[0] + ko, Ad + dstc[0]);
      gload_lds16(gAs[2] + ko, Ad + dstc[2]);
      asm volatile("s_waitcnt vmcnt(4)" ::: "memory");
    } else {
      asm volatile("s_waitcnt vmcnt(2)" ::: "memory");
    }
    __builtin_amdgcn_s_barrier();
    asm volatile("s_waitcnt lgkmcnt(0)" ::: "memory");
    __builtin_amdgcn_sched_barrier(0);
    MFMA_QUAD(0, 0, b0)

    // -------- phase 1: quadrant (mh0, nh1)
#pragma unroll
    for (int ni = 0; ni < 2; ++ni) {
      int lb = 128 + wc * 32 + ni * 16 + l16;
      b1[ni][0] = *(const bf16x8*)(Bc + lb * 64 + xk0);
      b1[ni][1] = *(const bf16x8*)(Bc + lb * 64 + xk1);
    }
    if (pf) {
      gload_lds16(gBs[0] + ko, Bd + dstc[0]);
      gload_lds16(gBs[1] + ko, Bd + dstc[1]);
      asm volatile("s_waitcnt vmcnt(4)" ::: "memory");
    } else {
      asm volatile("s_waitcnt vmcnt(0)" ::: "memory");
    }
    __builtin_amdgcn_s_barrier();
    asm volatile("s_waitcnt lgkmcnt(0)" ::: "memory");
    __builtin_amdgcn_sched_barrier(0);
    MFMA_QUAD(0, 1, b1)

    // -------- phase 2: quadrant (mh1, nh0)
#pragma unroll
    for (int mi = 0; mi < 4; ++mi) {
      int r = wr * 128 + 64 + mi * 16 + l16;
      aa[mi][0] = *(const bf16x8*)(Ac + r * 64 + xk0);
      aa[mi][1] = *(const bf16x8*)(Ac + r * 64 + xk1);
    }
    if (pf) {
      gload_lds16(gBs[2] + ko, Bd + dstc[2]);
      gload_lds16(gBs[3] + ko, Bd + dstc[3]);
      asm volatile("s_waitcnt vmcnt(4)" ::: "memory");
    }
    __builtin_amdgcn_s_barrier();
    asm volatile("s_waitcnt lgkmcnt(0)" ::: "memory");
    __builtin_amdgcn_sched_barrier(0);
    MFMA_QUAD(1, 0, b0)

    // -------- phase 3: quadrant (mh1, nh1) — no new LDS reads
    if (pf) {
      gload_lds16(gAs[1] + ko, Ad + dstc[1]);
      gload_lds16(gAs[3] + ko, Ad + dstc[3]);
      asm volatile("s_waitcnt vmcnt(4)" ::: "memory");
    }
    __builtin_amdgcn_s_barrier();
    MFMA_QUAD(1, 1, b1)

    cur ^= 1;
  }
#undef MFMA_QUAD

  // epilogue (C/D layout: col = lane&15, row = (lane>>4)*4 + reg)
  if constexpr (EPI == 2) {
    float* wvb = wv + (long)b * LQ_;
    float w3c[4];
#pragma unroll
    for (int n = 0; n < 4; ++n) w3c[n] = w3v[bn + wc * 64 + n * 16 + l16];
#pragma unroll
    for (int m = 0; m < 8; ++m)
#pragma unroll
      for (int rr = 0; rr < 4; ++rr) {
        float s = 0.f;
#pragma unroll
        for (int n = 0; n < 4; ++n)
          s += gelu_exact(acc[m][n][rr]) * w3c[n];
        s += __shfl_xor(s, 1);
        s += __shfl_xor(s, 2);
        s += __shfl_xor(s, 4);
        s += __shfl_xor(s, 8);
        if (l16 == 0)
          atomicAdd(&wvb[bm + wr * 128 + m * 16 + lhi * 4 + rr], s);
      }
  } else {
    Cc += (long)b * sC;
    const float* qnb = qn + (long)b * LQ_;
    const float* knb = kn + (long)b * LK_;
#pragma unroll
    for (int m = 0; m < 8; ++m) {
      int row0 = bm + wr * 128 + m * 16 + lhi * 4;
#pragma unroll
      for (int n = 0; n < 4; ++n) {
        int col = bn + wc * 64 + n * 16 + l16;
#pragma unroll
        for (int rr = 0; rr < 4; ++rr) {
          float v = acc[m][n][rr];
          int grow = row0 + rr;
          if (EPI == 0) {
            v = v / (qnb[grow] * knb[col] + 1e-2f);
          } else {
            v = gelu_exact(v);
          }
          Cc[(long)grow * 1024 + col] = f2bf(v);
        }
      }
    }
  }
}

// ---------------------------------------------------------------------------
// partial: wraw[b,k] += sum_{q in chunk} wv[b,q] * S[b,q,k]
__global__ __launch_bounds__(256) void gate_partial(const ushort* __restrict__ S,
                                                    const float* __restrict__ wv,
                                                    float* __restrict__ wraw) {
  int b = blockIdx.z;
  int k = blockIdx.x * 256 + threadIdx.x;
  int q0 = blockIdx.y * 128;
  const ushort* Sb = S + (long)b * LQ_ * LK_;
  const float* wb = wv + b * LQ_;
  float acc = 0.f;
#pragma unroll 4
  for (int q = q0; q < q0 + 128; ++q) acc += wb[q] * bf2f(Sb[(long)q * LK_ + k]);
  atomicAdd(&wraw[b * LK_ + k], acc);
}

// out[b,k,c] = value * (1 + tanh(wraw/32)); one float4 per thread
__global__ __launch_bounds__(256) void finalize(const float* __restrict__ value,
                                                const float* __restrict__ wraw,
                                                float* __restrict__ out) {
  long i = (long)blockIdx.x * 256 + threadIdx.x;  // float4 index
  long e = i * 4;
  int row = (int)(e >> 9);  // / 512
  float g = 1.f + tanhf(wraw[row] * (1.f / 32.f));
  float4 v = ((const float4*)value)[i];
  v.x *= g; v.y *= g; v.z *= g; v.w *= g;
  ((float4*)out)[i] = v;
}

// ---------------------------------------------------------------------------
extern "C" void kernel_launch(void* const* d_in, const int* in_sizes, int n_in,
                              void* d_out, int out_size, void* d_ws,
                              size_t ws_size, hipStream_t stream) {
  const float* query = (const float*)d_in[0];
  const float* key   = (const float*)d_in[1];
  const float* value = (const float*)d_in[2];
  const float* w1    = (const float*)d_in[3];
  const float* w2    = (const float*)d_in[4];
  const float* w3    = (const float*)d_in[5];
  float* out = (float*)d_out;

  // workspace layout (bytes)
  const size_t QB_BYTES = (size_t)B_ * LQ_ * C_ * 2;       // 16 MB
  const size_t S_BYTES  = (size_t)B_ * LQ_ * LK_ * 2;      // 32 MB
  const size_t W_BYTES  = (size_t)LK_ * LK_ * 2;           // 2 MB
  const size_t OFF_QB = 0;
  const size_t OFF_KB = OFF_QB + QB_BYTES;
  const size_t OFF_S  = OFF_KB + QB_BYTES;
  const size_t OFF_H1 = OFF_S + S_BYTES;
  const size_t OFF_W1 = OFF_H1 + S_BYTES;
  const size_t OFF_W2 = OFF_W1 + W_BYTES;
  const size_t OFF_QN = OFF_W2 + W_BYTES;
  const size_t OFF_KN = OFF_QN + (size_t)B_ * LQ_ * 4;
  const size_t OFF_WV = OFF_KN + (size_t)B_ * LK_ * 4;
  const size_t OFF_WR = OFF_WV + (size_t)B_ * LQ_ * 4;
  const size_t TOTAL  = OFF_WR + (size_t)B_ * LK_ * 4;
  if (ws_size < TOTAL) return;  // workspace too small; fail visibly

  char* ws = (char*)d_ws;
  ushort* Qb  = (ushort*)(ws + OFF_QB);
  ushort* Kb  = (ushort*)(ws + OFF_KB);
  ushort* S   = (ushort*)(ws + OFF_S);
  ushort* h1  = (ushort*)(ws + OFF_H1);
  ushort* W1b = (ushort*)(ws + OFF_W1);
  ushort* W2b = (ushort*)(ws + OFF_W2);
  float* qn   = (float*)(ws + OFF_QN);
  float* kn   = (float*)(ws + OFF_KN);
  float* wv   = (float*)(ws + OFF_WV);
  float* wraw = (float*)(ws + OFF_WR);

  // 1) prep: bf16 casts + norms
  prep_qk<<<dim3(B_ * LQ_ / 4), 256, 0, stream>>>(query, Qb, qn);
  prep_qk<<<dim3(B_ * LK_ / 4), 256, 0, stream>>>(key, Kb, kn);
  conv_bf16<<<dim3(LK_ * LK_ / 4 / 256), 256, 0, stream>>>(w1, W1b, LK_ * LK_ / 4);
  conv_bf16<<<dim3(LK_ * LK_ / 4 / 256), 256, 0, stream>>>(w2, W2b, LK_ * LK_ / 4);
  hipMemsetAsync(wraw, 0, (size_t)B_ * LK_ * 4, stream);
  hipMemsetAsync(wv, 0, (size_t)B_ * LQ_ * 4, stream);

  // 2) S = (Q K^T) / (|q||k| + 1e-2), bf16
  gemm256<0><<<dim3(256), 512, 0, stream>>>(
      Qb, Kb, S, C_, (long)LQ_ * C_, (long)LK_ * C_, (long)LQ_ * LK_,
      qn, kn, nullptr, nullptr);

  // 3) h1 = gelu(S @ W1^T)
  gemm256<1><<<dim3(256), 512, 0, stream>>>(
      S, W1b, h1, LK_, (long)LQ_ * LK_, 0L, (long)LQ_ * LK_,
      nullptr, nullptr, nullptr, nullptr);

  // 4) fused: wv[b,q] = dot(gelu(h1 @ W2^T)[q,:], w3)  (h2 never stored)
  gemm256<2><<<dim3(256), 512, 0, stream>>>(
      h1, W2b, nullptr, LK_, (long)LQ_ * LK_, 0L, 0L,
      nullptr, nullptr, w3, wv);

  // 5) wraw[b,k] = sum_q wv[b,q] * S[b,q,k]
  gate_partial<<<dim3(LK_ / 256, LQ_ / 128, B_), 256, 0, stream>>>(S, wv, wraw);

  // 6) out = value * (1 + tanh(wraw/32))
  finalize<<<dim3((size_t)B_ * LK_ * C_ / 4 / 256), 256, 0, stream>>>(value, wraw, out);
}